// Round 8
// baseline (580.493 us; speedup 1.0000x reference)
//
#include <hip/hip_runtime.h>

// LevelwiseSTA v8: deterministic radix multisplit (tile-hist + column scan +
// exact offsets) with XCD-contiguous chunk assignment, + wide LDS-local chain.
// Round-7 lessons: (a) stage1 was grid-starved (245 blocks, 42% occ) and
// write-inflated 2x (33B runs, adjacent runs written by different XCDs so
// partial sectors never merge in L2). v8: 496 blocks, deterministic layout
// ordered by chunk id, and chunks assigned XCD-contiguously so same-XCD
// adjacent sub-runs merge in that XCD's L2 before HBM. (b) chain at 512thr
// was gather-latency-bound -> 1024 threads, KPT=2.
//
// Invalid d = bf16(-3e30) sentinel: loses every max, underflows every exp;
// max <= -1e29 -> NEG_INF; fp32 absorption (-1e30 + d == -1e30) keeps
// reachability classification exactly equal to the reference.

#define NEG_INF  (-1e30f)
#define TAU_F    (0.07f)
#define INV_TAU  (1.0f / 0.07f)
#define BN    125         // nodes per bucket
#define GPL   250         // buckets (blocks) per level
#define NBK   8000        // total buckets = 1M / 125
#define CHUNK 16384
#define KPT   2           // stashed records per thread in chain (1024 thr)

typedef unsigned int uint;

__device__ __forceinline__ uint bf16_of(float f) {
    uint u = __float_as_uint(f);
    u += 0x7FFFu + ((u >> 16) & 1u);    // round to nearest even
    return u >> 16;
}
__device__ __forceinline__ float f_of_bf16(uint h) {
    return __uint_as_float((h & 0xFFFFu) << 16);
}
// monotone float<->uint; enc() != 0 for any real float, 0 == "empty"
__device__ __forceinline__ uint enc_f(float f) {
    uint u = __float_as_uint(f);
    return (u & 0x80000000u) ? ~u : (u | 0x80000000u);
}
__device__ __forceinline__ float dec_f(uint e) {
    uint u = (e & 0x80000000u) ? (e & 0x7FFFFFFFu) : ~e;
    return __uint_as_float(u);
}

// XCD-contiguous chunk id: XCD x (= blk%8, round-robin dispatch) owns
// chunks [x*nPer, (x+1)*nPer)
__device__ __forceinline__ int chunk_of(int blk, int nPer) {
    return (blk & 7) * nPer + (blk >> 3);
}

// ---------------------------------------------------------------- tile hist
__global__ __launch_bounds__(1024) void k_tilehist(
        const int* __restrict__ dst, int E, int nPer, int* __restrict__ hist) {
    __shared__ int h[NBK];
    const int t = threadIdx.x;
    const int c = chunk_of(blockIdx.x, nPer);
    for (int k = t; k < NBK; k += 1024) h[k] = 0;
    __syncthreads();
    const int bb = c * CHUNK;
#pragma unroll 4
    for (int k = 0; k < CHUNK / 1024; ++k) {
        int i = bb + k * 1024 + t;
        if (i < E) atomicAdd(&h[dst[i] / BN], 1);
    }
    __syncthreads();
    int* row = hist + (size_t)c * NBK;
    for (int k = t; k < NBK; k += 1024) row[k] = h[k];
}

// -------------------------------------------------- column scan (per bucket)
// off[c][b] = sum_{c'<c} hist[c'][b]; tot[b] = column sum. Loads coalesced
// across b; iterations independent of the accumulate -> prefetchable.
__global__ __launch_bounds__(256) void k_colscan(
        const int* __restrict__ hist, int nC,
        int* __restrict__ off, int* __restrict__ tot) {
    int b = blockIdx.x * 256 + threadIdx.x;
    if (b >= NBK) return;
    int cum = 0;
    for (int c = 0; c < nC; ++c) {
        int v = hist[(size_t)c * NBK + b];
        off[(size_t)c * NBK + b] = cum;
        cum += v;
    }
    tot[b] = cum;
}

// ------------------------------------------------------- bucket prefix scan
__global__ __launch_bounds__(1024) void k_scan(const int* __restrict__ tot,
                                               int* __restrict__ base) {
    __shared__ int sd[1024];
    int t = threadIdx.x;
    int v[8]; int s = 0;
#pragma unroll
    for (int k = 0; k < 8; ++k) {
        int i = t * 8 + k;
        v[k] = (i < NBK) ? tot[i] : 0;
        s += v[k];
    }
    sd[t] = s; __syncthreads();
    for (int o = 1; o < 1024; o <<= 1) {
        int x = 0; if (t >= o) x = sd[t - o];
        __syncthreads();
        sd[t] += x;
        __syncthreads();
    }
    int excl = sd[t] - s;
#pragma unroll
    for (int k = 0; k < 8; ++k) {
        int i = t * 8 + k;
        if (i < NBK) base[i] = excl;
        excl += v[k];
    }
    if (t == 1023) base[NBK] = sd[1023];
}

// ------------------------------------------------------------------ scatter
// Exact slot = base[b] + off[c][b] + LDS-cursor rank. Deterministic layout:
// bucket-major, sub-runs in chunk order -> same-XCD adjacency.
__global__ __launch_bounds__(1024) void k_scatter(
        const int* __restrict__ srcA, const int* __restrict__ dstA,
        const float4* __restrict__ dh, const float4* __restrict__ mk,
        int E, int nPer, const int* __restrict__ off,
        const int* __restrict__ base, uint4* __restrict__ recs) {
    __shared__ int h[NBK];
    const int t = threadIdx.x;
    const int c = chunk_of(blockIdx.x, nPer);
    const int* offrow = off + (size_t)c * NBK;
    for (int k = t; k < NBK; k += 1024) h[k] = base[k] + offrow[k];
    __syncthreads();
    const int bb = c * CHUNK;
    const uint INVB = bf16_of(-3e30f);
    for (int k = 0; k < CHUNK / 1024; ++k) {
        int i = bb + k * 1024 + t;
        if (i >= E) continue;
        int d = dstA[i];
        int b = d / BN;
        int pos = atomicAdd(&h[b], 1);
        float4 dv = dh[i];
        float4 mv = mk[i];
        uint e0 = (mv.x > 0.5f) ? bf16_of(dv.x * mv.x) : INVB;
        uint e1 = (mv.y > 0.5f) ? bf16_of(dv.y * mv.y) : INVB;
        uint e2 = (mv.z > 0.5f) ? bf16_of(dv.z * mv.z) : INVB;
        uint e3 = (mv.w > 0.5f) ? bf16_of(dv.w * mv.w) : INVB;
        uint4 r;
        r.x = (uint)srcA[i];
        r.y = (uint)(d - b * BN);
        r.z = e0 | (e1 << 16);
        r.w = e2 | (e3 << 16);
        recs[pos] = r;
    }
}

// -------------------------------------------------------------- level kernel
// One block per bucket (125 nodes), 1024 threads. Pass A: gather at[src]
// once, stash candidates in statically-indexed registers, LDS atomicMax.
// Pass B: from stash, LDS atomicAdd of exp((v-m)/tau). Cold tails never run
// (bucket count <= 2048 at +30 sigma).
__global__ __launch_bounds__(1024) void k_level(
        const uint4* __restrict__ recs, const int* __restrict__ base,
        float* __restrict__ at, int lvl) {
    int b = lvl * GPL + blockIdx.x;
    int j0 = base[b], j1 = base[b + 1];
    __shared__ uint  lm[BN * 2];
    __shared__ float ls[BN * 2];
    int t = threadIdx.x;
    if (t < BN * 2) { lm[t] = 0u; ls[t] = 0.f; }
    __syncthreads();

    float cr0[KPT], cr1[KPT], cf0[KPT], cf1[KPT];
    int nn[KPT];
#pragma unroll
    for (int k = 0; k < KPT; ++k) {
        int j = j0 + k * 1024 + t;
        nn[k] = -1;
        if (j < j1) {
            uint4 r = recs[j];
            float2 a = *(const float2*)(at + 2 * (size_t)r.x);
            cr0[k] = a.x + f_of_bf16(r.z);
            cf0[k] = a.x + f_of_bf16(r.z >> 16);
            cr1[k] = a.y + f_of_bf16(r.w);
            cf1[k] = a.y + f_of_bf16(r.w >> 16);
            int n2 = 2 * (int)r.y;
            nn[k] = n2;
            atomicMax(&lm[n2],     max(enc_f(cr0[k]), enc_f(cr1[k])));
            atomicMax(&lm[n2 + 1], max(enc_f(cf0[k]), enc_f(cf1[k])));
        }
    }
    for (int j = j0 + KPT * 1024 + t; j < j1; j += 1024) {   // cold tail
        uint4 r = recs[j];
        float2 a = *(const float2*)(at + 2 * (size_t)r.x);
        int n2 = 2 * (int)r.y;
        atomicMax(&lm[n2],     max(enc_f(a.x + f_of_bf16(r.z)),
                                   enc_f(a.y + f_of_bf16(r.w))));
        atomicMax(&lm[n2 + 1], max(enc_f(a.x + f_of_bf16(r.z >> 16)),
                                   enc_f(a.y + f_of_bf16(r.w >> 16))));
    }
    __syncthreads();

#pragma unroll
    for (int k = 0; k < KPT; ++k) {
        if (nn[k] >= 0) {
            float mr = dec_f(lm[nn[k]]);
            atomicAdd(&ls[nn[k]], __expf((cr0[k] - mr) * INV_TAU) +
                                  __expf((cr1[k] - mr) * INV_TAU));
            float mf = dec_f(lm[nn[k] + 1]);
            atomicAdd(&ls[nn[k] + 1], __expf((cf0[k] - mf) * INV_TAU) +
                                      __expf((cf1[k] - mf) * INV_TAU));
        }
    }
    for (int j = j0 + KPT * 1024 + t; j < j1; j += 1024) {   // cold tail
        uint4 r = recs[j];
        float2 a = *(const float2*)(at + 2 * (size_t)r.x);
        int n2 = 2 * (int)r.y;
        float mr = dec_f(lm[n2]);
        atomicAdd(&ls[n2], __expf((a.x + f_of_bf16(r.z) - mr) * INV_TAU) +
                           __expf((a.y + f_of_bf16(r.w) - mr) * INV_TAU));
        float mf = dec_f(lm[n2 + 1]);
        atomicAdd(&ls[n2 + 1], __expf((a.x + f_of_bf16(r.z >> 16) - mf) * INV_TAU) +
                               __expf((a.y + f_of_bf16(r.w >> 16) - mf) * INV_TAU));
    }
    __syncthreads();

    size_t obase = (size_t)b * (BN * 2);
    if (t < BN * 2) {
        uint e = lm[t];
        float v = NEG_INF;
        if (e != 0u) {
            float m = dec_f(e);
            if (m > -1e29f) v = m + TAU_F * __logf(ls[t]);
        }
        at[obase + t] = v;
    }
}

// -------------------------------------------------------------------- init
__global__ void k_init(const float2* __restrict__ ia, float2* __restrict__ at2,
                       int per) {
    int i = blockIdx.x * blockDim.x + threadIdx.x;
    if (i < per) at2[i] = ia[i];
}

// ---------------------------------------------------------------- endpoints
__global__ void k_ep(const float2* __restrict__ at2, const int* __restrict__ ep,
                     const float* __restrict__ rat, int M,
                     float* __restrict__ out_ep, float* __restrict__ out_slack) {
    int i = blockIdx.x * blockDim.x + threadIdx.x;
    int st = gridDim.x * blockDim.x;
    const float thr = NEG_INF + 1.0f;   // == -1e30f in fp32
    for (; i < M; i += st) {
        float2 a = at2[ep[i]];
        float sx = (a.x > thr) ? a.x : 0.f;
        float sy = (a.y > thr) ? a.y : 0.f;
        out_ep[2 * i]        = sx;
        out_ep[2 * i + 1]    = sy;
        out_slack[2 * i]     = rat[2 * i]     - sx;
        out_slack[2 * i + 1] = rat[2 * i + 1] - sy;
    }
}

extern "C" void kernel_launch(void* const* d_in, const int* in_sizes, int n_in,
                              void* d_out, int out_size, void* d_ws, size_t ws_size,
                              hipStream_t stream) {
    const float* d_hat         = (const float*)d_in[0];
    const float* sta_mask      = (const float*)d_in[1];
    const float* input_arrival = (const float*)d_in[2];
    const float* rat_true      = (const float*)d_in[3];
    const int*   edge_src      = (const int*)d_in[4];
    const int*   edge_dst      = (const int*)d_in[5];
    const int*   endpoint_ids  = (const int*)d_in[6];

    const int E = in_sizes[4];
    const int N = in_sizes[2] / 2;
    const int M = in_sizes[3] / 2;
    const int L = 32;                 // max_level = 31
    const int per = N / L;
    (void)n_in; (void)out_size; (void)ws_size;

    const int nChunk = (E + CHUNK - 1) / CHUNK;     // 489
    const int nPer   = (nChunk + 7) / 8;            // 62 chunks per XCD
    const int nC     = nPer * 8;                    // 496 (padded grid)

    char* ws = (char*)d_ws;
    size_t offb = 0;
    auto alloc = [&](size_t bytes) {
        void* p = ws + offb;
        offb = (offb + bytes + 255) & ~((size_t)255);
        return p;
    };
    int*   hist = (int*)alloc((size_t)nC * NBK * 4);   // ~15.9 MB
    int*   off  = (int*)alloc((size_t)nC * NBK * 4);   // ~15.9 MB
    int*   tot  = (int*)alloc((size_t)NBK * 4);
    int*   base = (int*)alloc((size_t)(NBK + 1) * 4);
    uint4* recs = (uint4*)alloc((size_t)E * 16);       // 128 MB, packed exactly

    float* at        = (float*)d_out;                  // at_all doubles as state
    float* out_ep    = at + 2 * (size_t)N;
    float* out_slack = out_ep + 2 * (size_t)M;

    k_init<<<(per + 255) / 256, 256, 0, stream>>>((const float2*)input_arrival,
                                                  (float2*)at, per);
    k_tilehist<<<nC, 1024, 0, stream>>>(edge_dst, E, nPer, hist);
    k_colscan<<<(NBK + 255) / 256, 256, 0, stream>>>(hist, nC, off, tot);
    k_scan<<<1, 1024, 0, stream>>>(tot, base);
    k_scatter<<<nC, 1024, 0, stream>>>(edge_src, edge_dst,
                                       (const float4*)d_hat, (const float4*)sta_mask,
                                       E, nPer, off, base, recs);

    for (int lvl = 1; lvl < L; ++lvl)
        k_level<<<GPL, 1024, 0, stream>>>(recs, base, at, lvl);

    k_ep<<<(M + 255) / 256, 256, 0, stream>>>((const float2*)at, endpoint_ids,
                                              rat_true, M, out_ep, out_slack);
}